// Round 1
// baseline (1217.149 us; speedup 1.0000x reference)
//
#include <hip/hip_runtime.h>

#define N_NODES   50000
#define N_EDGES   640000
#define DIM       128
#define N_LAYERS  5
#define N_GRAPHS  512
#define N_CLASSES 128
#define NB_SCAN   196   // ceil(N_NODES/256)

// ---------------- zero-init scratch accumulators (ws is poisoned 0xAA) -----
__global__ void k_zero(int* __restrict__ deg, int* __restrict__ fill,
                       float* __restrict__ pool, float* __restrict__ cnt) {
  int i = blockIdx.x * 256 + threadIdx.x;           // grid = 256 blocks -> 65536
  if (i < N_NODES) { deg[i] = 0; fill[i] = 0; }
  if (i < N_GRAPHS * DIM) pool[i] = 0.f;
  if (i < N_GRAPHS) cnt[i] = 0.f;
}

// ---------------- degree histogram over dst --------------------------------
__global__ void k_deg(const int* __restrict__ dst, int* __restrict__ deg) {
  int e = blockIdx.x * 256 + threadIdx.x;
  if (e < N_EDGES) atomicAdd(&deg[dst[e]], 1);
}

// ---------------- exclusive scan deg -> row_ptr (3 phases) -----------------
__global__ void k_scan1(const int* __restrict__ deg, int* __restrict__ bsum) {
  __shared__ int s[256];
  int t = threadIdx.x, i = blockIdx.x * 256 + t;
  s[t] = (i < N_NODES) ? deg[i] : 0;
  __syncthreads();
  for (int o = 128; o > 0; o >>= 1) {
    if (t < o) s[t] += s[t + o];
    __syncthreads();
  }
  if (t == 0) bsum[blockIdx.x] = s[0];
}

__global__ void k_scan2(int* __restrict__ bsum) {
  __shared__ int s[256];
  int t = threadIdx.x;
  s[t] = (t < NB_SCAN) ? bsum[t] : 0;
  __syncthreads();
  for (int o = 1; o < 256; o <<= 1) {
    int add = (t >= o) ? s[t - o] : 0;
    __syncthreads();
    s[t] += add;
    __syncthreads();
  }
  int ex = (t == 0) ? 0 : s[t - 1];
  if (t < NB_SCAN) bsum[t] = ex;
}

__global__ void k_scan3(const int* __restrict__ deg, const int* __restrict__ bsum,
                        int* __restrict__ row_ptr) {
  __shared__ int s[256];
  int t = threadIdx.x, i = blockIdx.x * 256 + t;
  s[t] = (i < N_NODES) ? deg[i] : 0;
  __syncthreads();
  for (int o = 1; o < 256; o <<= 1) {
    int add = (t >= o) ? s[t - o] : 0;
    __syncthreads();
    s[t] += add;
    __syncthreads();
  }
  int ex = bsum[blockIdx.x] + ((t == 0) ? 0 : s[t - 1]);
  if (i < N_NODES) row_ptr[i] = ex;
  if (blockIdx.x == 0 && t == 0) row_ptr[N_NODES] = N_EDGES;
}

// ---------------- CSR fill: col_src = src id, col_eid = edge id ------------
__global__ void k_fill(const int* __restrict__ src, const int* __restrict__ dst,
                       const int* __restrict__ row_ptr, int* __restrict__ fill,
                       int* __restrict__ col_src, int* __restrict__ col_eid) {
  int e = blockIdx.x * 256 + threadIdx.x;
  if (e < N_EDGES) {
    int d = dst[e];
    int pos = row_ptr[d] + atomicAdd(&fill[d], 1);
    col_src[pos] = src[e];
    col_eid[pos] = e;
  }
}

// -------- EAn = segsum(edge_attr,dst)/max(deg,1); rdeg; h = node_emb[x] ----
// 32 lanes per node (float4 -> 128 cols), 8 nodes per 256-thread block.
__global__ void k_ean_init(const int* __restrict__ row_ptr, const int* __restrict__ col_eid,
                           const float* __restrict__ edge_attr, const int* __restrict__ x,
                           const float* __restrict__ node_emb,
                           float* __restrict__ ean, float* __restrict__ rdeg,
                           float* __restrict__ h) {
  int sub = threadIdx.x >> 5;
  int lane = threadIdx.x & 31;
  int i = blockIdx.x * 8 + sub;
  if (i >= N_NODES) return;
  int b = row_ptr[i], e = row_ptr[i + 1];
  float4 acc = make_float4(0.f, 0.f, 0.f, 0.f);
  for (int p = b; p < e; p++) {
    int eid = col_eid[p];
    float4 v = ((const float4*)(edge_attr + (size_t)eid * DIM))[lane];
    acc.x += v.x; acc.y += v.y; acc.z += v.z; acc.w += v.w;
  }
  float r = 1.0f / (float)max(e - b, 1);
  if (lane == 0) rdeg[i] = r;
  float4 o = make_float4(acc.x * r, acc.y * r, acc.z * r, acc.w * r);
  ((float4*)(ean + (size_t)i * DIM))[lane] = o;
  float4 hv = ((const float4*)(node_emb + (size_t)x[i] * DIM))[lane];
  ((float4*)(h + (size_t)i * DIM))[lane] = hv;
}

// ---------------- u = h + (A h) / max(deg,1) -------------------------------
__global__ void k_gather(const int* __restrict__ row_ptr, const int* __restrict__ col_src,
                         const float* __restrict__ h, const float* __restrict__ rdeg,
                         float* __restrict__ u) {
  int sub = threadIdx.x >> 5;
  int lane = threadIdx.x & 31;
  int i = blockIdx.x * 8 + sub;
  if (i >= N_NODES) return;
  int b = row_ptr[i], e = row_ptr[i + 1];
  float4 acc = make_float4(0.f, 0.f, 0.f, 0.f);
  for (int p = b; p < e; p++) {
    int j = col_src[p];
    float4 v = ((const float4*)(h + (size_t)j * DIM))[lane];
    acc.x += v.x; acc.y += v.y; acc.z += v.z; acc.w += v.w;
  }
  float r = rdeg[i];
  float4 hv = ((const float4*)(h + (size_t)i * DIM))[lane];
  float4 o = make_float4(hv.x + acc.x * r, hv.y + acc.y * r,
                         hv.z + acc.z * r, hv.w + acc.w * r);
  ((float4*)(u + (size_t)i * DIM))[lane] = o;
}

// ------- h' = maybe_relu(u @ W0 + ean @ W1 + bias)  (fp32, LDS-tiled) ------
// Block: 128 rows x 128 cols, 256 threads, 8x8 register tile per thread.
__global__ __launch_bounds__(256) void k_gemm(
    const float* __restrict__ A0, const float* __restrict__ A1,
    const float* __restrict__ W0, const float* __restrict__ W1,
    const float* __restrict__ bias, float* __restrict__ hout, int relu) {
  __shared__ float sA[128][33];   // 32-wide K chunk, +1 pad
  __shared__ float sW[32][132];   // +4 pad
  int tx = threadIdx.x & 15;      // col base
  int ty = threadIdx.x >> 4;      // row base
  int row0 = blockIdx.x * 128;
  float acc[8][8] = {};

  for (int m = 0; m < 2; m++) {
    const float* A = m ? A1 : A0;
    const float* W = m ? W1 : W0;
    for (int k0 = 0; k0 < 128; k0 += 32) {
      // stage A tile: 128 rows x 32 k (16 floats/thread)
      {
        int r = threadIdx.x >> 1;
        int kg = (threadIdx.x & 1) * 16;
        int grow = row0 + r;
        float4 a0, a1, a2, a3;
        if (grow < N_NODES) {
          const float4* ap = (const float4*)(A + (size_t)grow * DIM + k0 + kg);
          a0 = ap[0]; a1 = ap[1]; a2 = ap[2]; a3 = ap[3];
        } else {
          a0 = a1 = a2 = a3 = make_float4(0.f, 0.f, 0.f, 0.f);
        }
        float* s = &sA[r][kg];
        s[0] = a0.x;  s[1] = a0.y;  s[2] = a0.z;  s[3] = a0.w;
        s[4] = a1.x;  s[5] = a1.y;  s[6] = a1.z;  s[7] = a1.w;
        s[8] = a2.x;  s[9] = a2.y;  s[10] = a2.z; s[11] = a2.w;
        s[12] = a3.x; s[13] = a3.y; s[14] = a3.z; s[15] = a3.w;
      }
      // stage W tile: 32 k x 128 cols (16 floats/thread)
      {
        int wr = threadIdx.x >> 3;
        int wc = (threadIdx.x & 7) * 16;
        const float4* wp = (const float4*)(W + (size_t)(k0 + wr) * DIM + wc);
        float4 w0 = wp[0], w1 = wp[1], w2 = wp[2], w3 = wp[3];
        float4* q = (float4*)(&sW[wr][wc]);
        q[0] = w0; q[1] = w1; q[2] = w2; q[3] = w3;
      }
      __syncthreads();
      #pragma unroll
      for (int kk = 0; kk < 32; kk++) {
        float av[8], wv[8];
        #pragma unroll
        for (int ri = 0; ri < 8; ri++) av[ri] = sA[ty + 16 * ri][kk];
        #pragma unroll
        for (int ci = 0; ci < 8; ci++) wv[ci] = sW[kk][tx + 16 * ci];
        #pragma unroll
        for (int ri = 0; ri < 8; ri++)
          #pragma unroll
          for (int ci = 0; ci < 8; ci++)
            acc[ri][ci] += av[ri] * wv[ci];
      }
      __syncthreads();
    }
  }
  #pragma unroll
  for (int ri = 0; ri < 8; ri++) {
    int r = row0 + ty + 16 * ri;
    if (r < N_NODES) {
      #pragma unroll
      for (int ci = 0; ci < 8; ci++) {
        int c = tx + 16 * ci;
        float v = acc[ri][ci] + bias[c];
        if (relu) v = fmaxf(v, 0.f);
        hout[(size_t)r * DIM + c] = v;
      }
    }
  }
}

// ---------------- mean-pool per graph (batch is sorted: run-length) --------
__global__ void k_pool(const float* __restrict__ h, const int* __restrict__ batch,
                       float* __restrict__ pool, float* __restrict__ cnt) {
  int t = threadIdx.x;                 // column 0..127
  int i0 = blockIdx.x * 128;
  int iend = min(i0 + 128, N_NODES);
  float acc = 0.f;
  int cur = -1, run = 0;
  for (int i = i0; i < iend; i++) {
    int g = batch[i];
    if (g != cur) {
      if (cur >= 0) {
        atomicAdd(&pool[(size_t)cur * DIM + t], acc);
        if (t == 0) atomicAdd(&cnt[cur], (float)run);
      }
      acc = 0.f; run = 0; cur = g;
    }
    acc += h[(size_t)i * DIM + t];
    run++;
  }
  if (cur >= 0) {
    atomicAdd(&pool[(size_t)cur * DIM + t], acc);
    if (t == 0) atomicAdd(&cnt[cur], (float)run);
  }
}

// ---------------- out = (pool/cnt) @ Wp + bp -------------------------------
__global__ void k_out(const float* __restrict__ pool, const float* __restrict__ cnt,
                      const float* __restrict__ Wp, const float* __restrict__ bp,
                      float* __restrict__ out) {
  __shared__ float sp[DIM];
  int g = blockIdx.x, t = threadIdx.x;
  sp[t] = pool[(size_t)g * DIM + t];
  __syncthreads();
  float r = 1.0f / fmaxf(cnt[g], 1.0f);
  float acc = 0.f;
  for (int k = 0; k < DIM; k++) acc += sp[k] * Wp[(size_t)k * N_CLASSES + t];
  out[(size_t)g * N_CLASSES + t] = acc * r + bp[t];
}

extern "C" void kernel_launch(void* const* d_in, const int* in_sizes, int n_in,
                              void* d_out, int out_size, void* d_ws, size_t ws_size,
                              hipStream_t stream) {
  (void)in_sizes; (void)n_in; (void)out_size; (void)ws_size;
  const int*   x          = (const int*)d_in[0];
  const int*   edge_index = (const int*)d_in[1];
  const float* edge_attr  = (const float*)d_in[2];
  const int*   batch      = (const int*)d_in[3];
  const float* node_emb   = (const float*)d_in[4];
  const float* Ws         = (const float*)d_in[5];
  const float* bs         = (const float*)d_in[6];
  const float* Wes        = (const float*)d_in[7];
  const float* Wp         = (const float*)d_in[8];
  const float* bp         = (const float*)d_in[9];
  float* out = (float*)d_out;
  const int* src = edge_index;
  const int* dst = edge_index + N_EDGES;

  char* p = (char*)d_ws;
  auto alloc = [&](size_t bytes) {
    void* q = (void*)p;
    p += (bytes + 255) & ~(size_t)255;
    return q;
  };
  float* h       = (float*)alloc((size_t)N_NODES * DIM * 4);
  float* u       = (float*)alloc((size_t)N_NODES * DIM * 4);
  float* ean     = (float*)alloc((size_t)N_NODES * DIM * 4);
  int*   deg     = (int*)  alloc((size_t)N_NODES * 4);
  float* rdeg    = (float*)alloc((size_t)N_NODES * 4);
  int*   row_ptr = (int*)  alloc((size_t)(N_NODES + 64) * 4);
  int*   fill    = (int*)  alloc((size_t)N_NODES * 4);
  int*   col_src = (int*)  alloc((size_t)N_EDGES * 4);
  int*   col_eid = (int*)  alloc((size_t)N_EDGES * 4);
  float* pool    = (float*)alloc((size_t)N_GRAPHS * DIM * 4);
  float* cnt     = (float*)alloc((size_t)N_GRAPHS * 4);
  int*   bsum    = (int*)  alloc(256 * 4);

  k_zero<<<256, 256, 0, stream>>>(deg, fill, pool, cnt);
  k_deg<<<(N_EDGES + 255) / 256, 256, 0, stream>>>(dst, deg);
  k_scan1<<<NB_SCAN, 256, 0, stream>>>(deg, bsum);
  k_scan2<<<1, 256, 0, stream>>>(bsum);
  k_scan3<<<NB_SCAN, 256, 0, stream>>>(deg, bsum, row_ptr);
  k_fill<<<(N_EDGES + 255) / 256, 256, 0, stream>>>(src, dst, row_ptr, fill, col_src, col_eid);
  k_ean_init<<<(N_NODES + 7) / 8, 256, 0, stream>>>(row_ptr, col_eid, edge_attr, x,
                                                    node_emb, ean, rdeg, h);
  for (int l = 0; l < N_LAYERS; l++) {
    k_gather<<<(N_NODES + 7) / 8, 256, 0, stream>>>(row_ptr, col_src, h, rdeg, u);
    k_gemm<<<(N_NODES + 127) / 128, 256, 0, stream>>>(
        u, ean, Ws + (size_t)l * DIM * DIM, Wes + (size_t)l * DIM * DIM,
        bs + (size_t)l * DIM, h, (l < N_LAYERS - 1) ? 1 : 0);
  }
  k_pool<<<(N_NODES + 127) / 128, 128, 0, stream>>>(h, batch, pool, cnt);
  k_out<<<N_GRAPHS, N_CLASSES, 0, stream>>>(pool, cnt, Wp, bp, out);
}

// Round 3
// 869.330 us; speedup vs baseline: 1.4001x; 1.4001x over previous
//
#include <hip/hip_runtime.h>

#define N_NODES   50000
#define N_EDGES   640000
#define DIM       128
#define N_LAYERS  5
#define N_GRAPHS  512
#define N_CLASSES 128
#define NB_SCAN   196   // ceil(N_NODES/256)

typedef __attribute__((ext_vector_type(8))) short short8;     // 8 bf16 (4 VGPRs)
typedef __attribute__((ext_vector_type(4))) float floatx4;    // MFMA acc

__device__ inline float bfhi(unsigned u) { return __uint_as_float(u & 0xffff0000u); }
__device__ inline float bflo(unsigned u) { return __uint_as_float(u << 16); }
__device__ inline unsigned f2bf(float f) {          // round-to-nearest-even
  unsigned x = __float_as_uint(f);
  return (x + 0x7fffu + ((x >> 16) & 1u)) >> 16;
}

// ---------------- zero-init scratch accumulators (ws is poisoned 0xAA) -----
__global__ void k_zero(int* __restrict__ deg, int* __restrict__ fill,
                       float* __restrict__ pool, float* __restrict__ cnt) {
  int i = blockIdx.x * 256 + threadIdx.x;
  if (i < N_NODES) { deg[i] = 0; fill[i] = 0; }
  if (i < N_GRAPHS * DIM) pool[i] = 0.f;
  if (i < N_GRAPHS) cnt[i] = 0.f;
}

// ---------------- degree histogram over dst --------------------------------
__global__ void k_deg(const int* __restrict__ dst, int* __restrict__ deg) {
  int e = blockIdx.x * 256 + threadIdx.x;
  if (e < N_EDGES) atomicAdd(&deg[dst[e]], 1);
}

// ---------------- exclusive scan deg -> row_ptr (3 phases) -----------------
__global__ void k_scan1(const int* __restrict__ deg, int* __restrict__ bsum) {
  __shared__ int s[256];
  int t = threadIdx.x, i = blockIdx.x * 256 + t;
  s[t] = (i < N_NODES) ? deg[i] : 0;
  __syncthreads();
  for (int o = 128; o > 0; o >>= 1) {
    if (t < o) s[t] += s[t + o];
    __syncthreads();
  }
  if (t == 0) bsum[blockIdx.x] = s[0];
}

__global__ void k_scan2(int* __restrict__ bsum) {
  __shared__ int s[256];
  int t = threadIdx.x;
  s[t] = (t < NB_SCAN) ? bsum[t] : 0;
  __syncthreads();
  for (int o = 1; o < 256; o <<= 1) {
    int add = (t >= o) ? s[t - o] : 0;
    __syncthreads();
    s[t] += add;
    __syncthreads();
  }
  int ex = (t == 0) ? 0 : s[t - 1];
  if (t < NB_SCAN) bsum[t] = ex;
}

__global__ void k_scan3(const int* __restrict__ deg, const int* __restrict__ bsum,
                        int* __restrict__ row_ptr) {
  __shared__ int s[256];
  int t = threadIdx.x, i = blockIdx.x * 256 + t;
  s[t] = (i < N_NODES) ? deg[i] : 0;
  __syncthreads();
  for (int o = 1; o < 256; o <<= 1) {
    int add = (t >= o) ? s[t - o] : 0;
    __syncthreads();
    s[t] += add;
    __syncthreads();
  }
  int ex = bsum[blockIdx.x] + ((t == 0) ? 0 : s[t - 1]);
  if (i < N_NODES) row_ptr[i] = ex;
  if (blockIdx.x == 0 && t == 0) row_ptr[N_NODES] = N_EDGES;
}

// ---------------- CSR fill -------------------------------------------------
__global__ void k_fill(const int* __restrict__ src, const int* __restrict__ dst,
                       const int* __restrict__ row_ptr, int* __restrict__ fill,
                       int* __restrict__ col_src, int* __restrict__ col_eid) {
  int e = blockIdx.x * 256 + threadIdx.x;
  if (e < N_EDGES) {
    int d = dst[e];
    int pos = row_ptr[d] + atomicAdd(&fill[d], 1);
    col_src[pos] = src[e];
    col_eid[pos] = e;
  }
}

// ------- weights: bf16 + transpose:  Wt[l][c][k] = W[l][k][c] --------------
__global__ void k_wconv(const float* __restrict__ Ws, const float* __restrict__ Wes,
                        unsigned short* __restrict__ Wt_s, unsigned short* __restrict__ Wt_e) {
  int idx = blockIdx.x * 256 + threadIdx.x;          // total 2*5*128*128 = 163840
  int which = idx / (N_LAYERS * DIM * DIM);
  int rem = idx - which * (N_LAYERS * DIM * DIM);
  int l = rem >> 14;            // /16384
  int c = (rem >> 7) & 127;
  int k = rem & 127;
  const float* W = which ? Wes : Ws;
  unsigned short* O = which ? Wt_e : Wt_s;
  float v = W[((size_t)l * DIM + k) * DIM + c];
  O[((size_t)l * DIM + c) * DIM + k] = (unsigned short)f2bf(v);
}

// -------- EAn = segsum(edge_attr,dst)/max(deg,1) (bf16); rdeg; h init ------
// 32 lanes per node (float4 -> 128 cols), 8 nodes per 256-thread block.
__global__ void k_ean_init(const int* __restrict__ row_ptr, const int* __restrict__ col_eid,
                           const float* __restrict__ edge_attr, const int* __restrict__ x,
                           const float* __restrict__ node_emb,
                           unsigned short* __restrict__ ean, float* __restrict__ rdeg,
                           unsigned short* __restrict__ h) {
  int sub = threadIdx.x >> 5;
  int lane = threadIdx.x & 31;
  int i = blockIdx.x * 8 + sub;
  if (i >= N_NODES) return;
  int b = row_ptr[i], e = row_ptr[i + 1];
  float4 acc = make_float4(0.f, 0.f, 0.f, 0.f);
  for (int p = b; p < e; p++) {
    int eid = col_eid[p];
    float4 v = ((const float4*)(edge_attr + (size_t)eid * DIM))[lane];
    acc.x += v.x; acc.y += v.y; acc.z += v.z; acc.w += v.w;
  }
  float r = 1.0f / (float)max(e - b, 1);
  if (lane == 0) rdeg[i] = r;
  uint2 o;
  o.x = f2bf(acc.x * r) | (f2bf(acc.y * r) << 16);
  o.y = f2bf(acc.z * r) | (f2bf(acc.w * r) << 16);
  ((uint2*)(ean + (size_t)i * DIM))[lane] = o;
  float4 hv = ((const float4*)(node_emb + (size_t)x[i] * DIM))[lane];
  uint2 ho;
  ho.x = f2bf(hv.x) | (f2bf(hv.y) << 16);
  ho.y = f2bf(hv.z) | (f2bf(hv.w) << 16);
  ((uint2*)(h + (size_t)i * DIM))[lane] = ho;
}

// ---------------- u = h + (A h) / max(deg,1)  (bf16 in/out, fp32 acc) ------
// 16 lanes per node (uint4 = 8 bf16 per lane), 16 nodes per 256-thread block.
__global__ void k_gather(const int* __restrict__ row_ptr, const int* __restrict__ col_src,
                         const unsigned short* __restrict__ h, const float* __restrict__ rdeg,
                         unsigned short* __restrict__ u) {
  int sub = threadIdx.x >> 4;
  int lane = threadIdx.x & 15;
  int i = blockIdx.x * 16 + sub;
  if (i >= N_NODES) return;
  int b = row_ptr[i], e = row_ptr[i + 1];
  float a0 = 0.f, a1 = 0.f, a2 = 0.f, a3 = 0.f, a4 = 0.f, a5 = 0.f, a6 = 0.f, a7 = 0.f;
  for (int p = b; p < e; p++) {
    int j = col_src[p];
    uint4 v = *(const uint4*)(h + (size_t)j * DIM + lane * 8);
    a0 += bflo(v.x); a1 += bfhi(v.x);
    a2 += bflo(v.y); a3 += bfhi(v.y);
    a4 += bflo(v.z); a5 += bfhi(v.z);
    a6 += bflo(v.w); a7 += bfhi(v.w);
  }
  float r = rdeg[i];
  uint4 hv = *(const uint4*)(h + (size_t)i * DIM + lane * 8);
  uint4 o;
  o.x = f2bf(bflo(hv.x) + a0 * r) | (f2bf(bfhi(hv.x) + a1 * r) << 16);
  o.y = f2bf(bflo(hv.y) + a2 * r) | (f2bf(bfhi(hv.y) + a3 * r) << 16);
  o.z = f2bf(bflo(hv.z) + a4 * r) | (f2bf(bfhi(hv.z) + a5 * r) << 16);
  o.w = f2bf(bflo(hv.w) + a6 * r) | (f2bf(bfhi(hv.w) + a7 * r) << 16);
  *(uint4*)(u + (size_t)i * DIM + lane * 8) = o;
}

// ------- h' = maybe_relu(u @ W0 + ean @ W1 + bias)  MFMA bf16 --------------
// Block: 64 rows x 128 cols, 256 threads = 4 waves, each wave one 16-row strip.
__global__ __launch_bounds__(256) void k_gemm(
    const unsigned short* __restrict__ A0, const unsigned short* __restrict__ A1,
    const unsigned short* __restrict__ W0, const unsigned short* __restrict__ W1,
    const float* __restrict__ bias, unsigned short* __restrict__ hout, int relu) {
  __shared__ unsigned short sA[64][72];    // 64 rows x 64-k chunk, +8 pad
  __shared__ unsigned short sW[128][72];   // 128 cols x 64-k chunk (Wt layout)
  int tid = threadIdx.x;
  int wave = tid >> 6, lane = tid & 63;
  int quad = lane >> 4, l16 = lane & 15;
  int row0 = blockIdx.x * 64;
  floatx4 acc[8];
  #pragma unroll
  for (int ci = 0; ci < 8; ci++) acc[ci] = (floatx4){0.f, 0.f, 0.f, 0.f};

  for (int m = 0; m < 2; m++) {
    const unsigned short* A = m ? A1 : A0;
    const unsigned short* W = m ? W1 : W0;
    for (int kc = 0; kc < 128; kc += 64) {
      __syncthreads();
      // stage A: 64 rows x 64 shorts = 512 uint4, 2 per thread
      #pragma unroll
      for (int q = 0; q < 2; q++) {
        int s = tid + 256 * q;
        int r = s >> 3, seg = s & 7;
        int grow = row0 + r;
        uint4 v = make_uint4(0u, 0u, 0u, 0u);
        if (grow < N_NODES)
          v = *(const uint4*)(A + (size_t)grow * DIM + kc + seg * 8);
        *(uint4*)(&sA[r][seg * 8]) = v;
      }
      // stage W: 128 rows x 64 shorts = 1024 uint4, 4 per thread
      #pragma unroll
      for (int q = 0; q < 4; q++) {
        int s = tid + 256 * q;
        int r = s >> 3, seg = s & 7;
        *(uint4*)(&sW[r][seg * 8]) =
            *(const uint4*)(W + (size_t)r * DIM + kc + seg * 8);
      }
      __syncthreads();
      #pragma unroll
      for (int ks = 0; ks < 64; ks += 32) {
        short8 a = *(const short8*)(&sA[wave * 16 + l16][ks + quad * 8]);
        #pragma unroll
        for (int ci = 0; ci < 8; ci++) {
          short8 b = *(const short8*)(&sW[ci * 16 + l16][ks + quad * 8]);
          acc[ci] = __builtin_amdgcn_mfma_f32_16x16x32_bf16(a, b, acc[ci], 0, 0, 0);
        }
      }
    }
  }
  // epilogue: row = row0 + wave*16 + quad*4 + r ; col = ci*16 + l16
  #pragma unroll
  for (int ci = 0; ci < 8; ci++) {
    int col = ci * 16 + l16;
    float bv = bias[col];
    #pragma unroll
    for (int r = 0; r < 4; r++) {
      int row = row0 + wave * 16 + quad * 4 + r;
      if (row < N_NODES) {
        float v = acc[ci][r] + bv;
        if (relu) v = fmaxf(v, 0.f);
        hout[(size_t)row * DIM + col] = (unsigned short)f2bf(v);
      }
    }
  }
}

// ---------------- mean-pool per graph (batch sorted: run-length) -----------
__global__ void k_pool(const unsigned short* __restrict__ h, const int* __restrict__ batch,
                       float* __restrict__ pool, float* __restrict__ cnt) {
  int t = threadIdx.x;                 // column 0..127
  int i0 = blockIdx.x * 128;
  int iend = min(i0 + 128, N_NODES);
  float acc = 0.f;
  int cur = -1, run = 0;
  for (int i = i0; i < iend; i++) {
    int g = batch[i];
    if (g != cur) {
      if (cur >= 0) {
        atomicAdd(&pool[(size_t)cur * DIM + t], acc);
        if (t == 0) atomicAdd(&cnt[cur], (float)run);
      }
      acc = 0.f; run = 0; cur = g;
    }
    acc += __uint_as_float(((unsigned)h[(size_t)i * DIM + t]) << 16);
    run++;
  }
  if (cur >= 0) {
    atomicAdd(&pool[(size_t)cur * DIM + t], acc);
    if (t == 0) atomicAdd(&cnt[cur], (float)run);
  }
}

// ---------------- out = (pool/cnt) @ Wp + bp -------------------------------
__global__ void k_out(const float* __restrict__ pool, const float* __restrict__ cnt,
                      const float* __restrict__ Wp, const float* __restrict__ bp,
                      float* __restrict__ out) {
  __shared__ float sp[DIM];
  int g = blockIdx.x, t = threadIdx.x;
  sp[t] = pool[(size_t)g * DIM + t];
  __syncthreads();
  float r = 1.0f / fmaxf(cnt[g], 1.0f);
  float acc = 0.f;
  for (int k = 0; k < DIM; k++) acc += sp[k] * Wp[(size_t)k * N_CLASSES + t];
  out[(size_t)g * N_CLASSES + t] = acc * r + bp[t];
}

extern "C" void kernel_launch(void* const* d_in, const int* in_sizes, int n_in,
                              void* d_out, int out_size, void* d_ws, size_t ws_size,
                              hipStream_t stream) {
  (void)in_sizes; (void)n_in; (void)out_size; (void)ws_size;
  const int*   x          = (const int*)d_in[0];
  const int*   edge_index = (const int*)d_in[1];
  const float* edge_attr  = (const float*)d_in[2];
  const int*   batch      = (const int*)d_in[3];
  const float* node_emb   = (const float*)d_in[4];
  const float* Ws         = (const float*)d_in[5];
  const float* bs         = (const float*)d_in[6];
  const float* Wes        = (const float*)d_in[7];
  const float* Wp         = (const float*)d_in[8];
  const float* bp         = (const float*)d_in[9];
  float* out = (float*)d_out;
  const int* src = edge_index;
  const int* dst = edge_index + N_EDGES;

  char* p = (char*)d_ws;
  auto alloc = [&](size_t bytes) {
    void* q = (void*)p;
    p += (bytes + 255) & ~(size_t)255;
    return q;
  };
  unsigned short* h    = (unsigned short*)alloc((size_t)N_NODES * DIM * 2);
  unsigned short* u    = (unsigned short*)alloc((size_t)N_NODES * DIM * 2);
  unsigned short* ean  = (unsigned short*)alloc((size_t)N_NODES * DIM * 2);
  unsigned short* Wt_s = (unsigned short*)alloc((size_t)N_LAYERS * DIM * DIM * 2);
  unsigned short* Wt_e = (unsigned short*)alloc((size_t)N_LAYERS * DIM * DIM * 2);
  int*   deg     = (int*)  alloc((size_t)N_NODES * 4);
  float* rdeg    = (float*)alloc((size_t)N_NODES * 4);
  int*   row_ptr = (int*)  alloc((size_t)(N_NODES + 64) * 4);
  int*   fill    = (int*)  alloc((size_t)N_NODES * 4);
  int*   col_src = (int*)  alloc((size_t)N_EDGES * 4);
  int*   col_eid = (int*)  alloc((size_t)N_EDGES * 4);
  float* pool    = (float*)alloc((size_t)N_GRAPHS * DIM * 4);
  float* cnt     = (float*)alloc((size_t)N_GRAPHS * 4);
  int*   bsum    = (int*)  alloc(256 * 4);

  k_zero<<<256, 256, 0, stream>>>(deg, fill, pool, cnt);
  k_deg<<<(N_EDGES + 255) / 256, 256, 0, stream>>>(dst, deg);
  k_scan1<<<NB_SCAN, 256, 0, stream>>>(deg, bsum);
  k_scan2<<<1, 256, 0, stream>>>(bsum);
  k_scan3<<<NB_SCAN, 256, 0, stream>>>(deg, bsum, row_ptr);
  k_fill<<<(N_EDGES + 255) / 256, 256, 0, stream>>>(src, dst, row_ptr, fill, col_src, col_eid);
  k_wconv<<<(2 * N_LAYERS * DIM * DIM) / 256, 256, 0, stream>>>(Ws, Wes, Wt_s, Wt_e);
  k_ean_init<<<(N_NODES + 7) / 8, 256, 0, stream>>>(row_ptr, col_eid, edge_attr, x,
                                                    node_emb, ean, rdeg, h);
  for (int l = 0; l < N_LAYERS; l++) {
    k_gather<<<(N_NODES + 15) / 16, 256, 0, stream>>>(row_ptr, col_src, h, rdeg, u);
    k_gemm<<<(N_NODES + 63) / 64, 256, 0, stream>>>(
        u, ean, Wt_s + (size_t)l * DIM * DIM, Wt_e + (size_t)l * DIM * DIM,
        bs + (size_t)l * DIM, h, (l < N_LAYERS - 1) ? 1 : 0);
  }
  k_pool<<<(N_NODES + 127) / 128, 128, 0, stream>>>(h, batch, pool, cnt);
  k_out<<<N_GRAPHS, N_CLASSES, 0, stream>>>(pool, cnt, Wp, bp, out);
}